// Round 1
// baseline (574.490 us; speedup 1.0000x reference)
//
#include <hip/hip_runtime.h>

#define N 8192
#define D 256
#define TM 64
#define TN 64
#define DK 32
#define JSPLIT 8
#define JCHUNK (N / JSPLIT)
#define NEG_INF (-__builtin_inff())

// ---------------------------------------------------------------- kernel 1
// sq[i] = sum_d q[i][d]^2 ; one wave per row
__global__ __launch_bounds__(256) void sq_kernel(const float* __restrict__ q,
                                                 float* __restrict__ sq) {
    const int row = blockIdx.x * 4 + (threadIdx.x >> 6);
    const int lane = threadIdx.x & 63;
    const float4 v = ((const float4*)(q + row * D))[lane];
    float s = v.x * v.x + v.y * v.y + v.z * v.z + v.w * v.w;
    #pragma unroll
    for (int off = 32; off; off >>= 1) s += __shfl_down(s, off, 64);
    if (lane == 0) sq[row] = s;
}

// ---------------------------------------------------------------- kernel 2
// For rows [i0,i0+64) and j in this split's range, compute dist[i][j] =
// sq_i + sq_j - 2*dot and track argmax of the pos/neg masked matrices.
// Exact jnp.argmax (first occurrence) semantics via strict > within a
// thread's monotone j scan + (val, smaller idx) tie-break across lanes.
__global__ __launch_bounds__(256) void mine_kernel(
    const float* __restrict__ q, const int* __restrict__ tgt,
    const float* __restrict__ sqv,
    float* __restrict__ pos_val, float* __restrict__ neg_val,
    int* __restrict__ pos_idx, int* __restrict__ neg_idx)
{
    __shared__ float As[DK][TM];   // d-major: conflict-light compute reads
    __shared__ float Bs[DK][TN];

    const int i0 = blockIdx.x * TM;
    const int split = blockIdx.y;
    const int jbase = split * JCHUNK;

    const int tid = threadIdx.x;
    const int tx = tid & 15;       // 16 threads across columns
    const int ty = tid >> 4;       // 16 thread-rows

    const int ldr = tid >> 2;      // staging: row within tile (0..63)
    const int ldd = (tid & 3) * 8; // staging: d offset within chunk

    int irow[4]; float sqi[4]; int ti[4];
    float bpv[4], bnv[4]; int bpi[4], bni[4];
    #pragma unroll
    for (int m = 0; m < 4; ++m) {
        irow[m] = i0 + ty * 4 + m;
        sqi[m] = sqv[irow[m]];
        ti[m] = tgt[irow[m]];
        bpv[m] = NEG_INF; bnv[m] = NEG_INF;
        bpi[m] = 0x7FFFFFFF; bni[m] = 0x7FFFFFFF;
    }

    for (int jt = 0; jt < JCHUNK; jt += TN) {
        const int j0 = jbase + jt;
        float acc[4][4];
        #pragma unroll
        for (int m = 0; m < 4; ++m)
            #pragma unroll
            for (int n = 0; n < 4; ++n) acc[m][n] = 0.0f;

        for (int dk = 0; dk < D; dk += DK) {
            const float* pa = q + (i0 + ldr) * D + dk + ldd;
            const float* pb = q + (j0 + ldr) * D + dk + ldd;
            const float4 a0 = *(const float4*)(pa);
            const float4 a1 = *(const float4*)(pa + 4);
            const float4 b0 = *(const float4*)(pb);
            const float4 b1 = *(const float4*)(pb + 4);
            __syncthreads();   // previous chunk's reads done before overwrite
            As[ldd + 0][ldr] = a0.x; As[ldd + 1][ldr] = a0.y;
            As[ldd + 2][ldr] = a0.z; As[ldd + 3][ldr] = a0.w;
            As[ldd + 4][ldr] = a1.x; As[ldd + 5][ldr] = a1.y;
            As[ldd + 6][ldr] = a1.z; As[ldd + 7][ldr] = a1.w;
            Bs[ldd + 0][ldr] = b0.x; Bs[ldd + 1][ldr] = b0.y;
            Bs[ldd + 2][ldr] = b0.z; Bs[ldd + 3][ldr] = b0.w;
            Bs[ldd + 4][ldr] = b1.x; Bs[ldd + 5][ldr] = b1.y;
            Bs[ldd + 6][ldr] = b1.z; Bs[ldd + 7][ldr] = b1.w;
            __syncthreads();
            #pragma unroll
            for (int d = 0; d < DK; ++d) {
                const float4 av = *(const float4*)&As[d][ty * 4]; // broadcast over tx
                const float4 bv = *(const float4*)&Bs[d][tx * 4];
                acc[0][0] += av.x * bv.x; acc[0][1] += av.x * bv.y;
                acc[0][2] += av.x * bv.z; acc[0][3] += av.x * bv.w;
                acc[1][0] += av.y * bv.x; acc[1][1] += av.y * bv.y;
                acc[1][2] += av.y * bv.z; acc[1][3] += av.y * bv.w;
                acc[2][0] += av.z * bv.x; acc[2][1] += av.z * bv.y;
                acc[2][2] += av.z * bv.z; acc[2][3] += av.z * bv.w;
                acc[3][0] += av.w * bv.x; acc[3][1] += av.w * bv.y;
                acc[3][2] += av.w * bv.z; acc[3][3] += av.w * bv.w;
            }
        }

        // epilogue: masked argmax update for this 64x64 tile
        #pragma unroll
        for (int n = 0; n < 4; ++n) {
            const int jj = j0 + tx * 4 + n;
            const float sqj = sqv[jj];
            const int tj = tgt[jj];
            #pragma unroll
            for (int m = 0; m < 4; ++m) {
                const float dist = sqi[m] + sqj - 2.0f * acc[m][n];
                const bool dia = (irow[m] == jj);
                const bool same = (ti[m] == tj);
                const float vp = dia ? NEG_INF : (same ? dist : 0.0f);
                const float vn = dia ? NEG_INF : (same ? 0.0f : dist);
                if (vp > bpv[m]) { bpv[m] = vp; bpi[m] = jj; } // strict >: keeps first
                if (vn > bnv[m]) { bnv[m] = vn; bni[m] = jj; }
            }
        }
    }

    // reduce across the 16 lanes (same ty group, contiguous lanes in one wave)
    #pragma unroll
    for (int m = 0; m < 4; ++m) {
        #pragma unroll
        for (int off = 8; off; off >>= 1) {
            const float pv = __shfl_xor(bpv[m], off, 64);
            const int   pi = __shfl_xor(bpi[m], off, 64);
            if (pv > bpv[m] || (pv == bpv[m] && pi < bpi[m])) { bpv[m] = pv; bpi[m] = pi; }
            const float nv = __shfl_xor(bnv[m], off, 64);
            const int   ni = __shfl_xor(bni[m], off, 64);
            if (nv > bnv[m] || (nv == bnv[m] && ni < bni[m])) { bnv[m] = nv; bni[m] = ni; }
        }
        if (tx == 0) {
            const int row = irow[m];
            pos_val[split * N + row] = bpv[m];
            pos_idx[split * N + row] = bpi[m];
            neg_val[split * N + row] = bnv[m];
            neg_idx[split * N + row] = bni[m];
        }
    }
}

// ---------------------------------------------------------------- kernel 3
// Merge split partials (in split order => index order), recompute direct
// squared distances like the reference, write per-row loss.
__global__ __launch_bounds__(256) void finalize_kernel(
    const float* __restrict__ q,
    const float* __restrict__ pos_val, const float* __restrict__ neg_val,
    const int* __restrict__ pos_idx, const int* __restrict__ neg_idx,
    float* __restrict__ loss)
{
    const int row = blockIdx.x * 4 + (threadIdx.x >> 6);
    const int lane = threadIdx.x & 63;

    float bpv = NEG_INF, bnv = NEG_INF;
    int bpi = 0x7FFFFFFF, bni = 0x7FFFFFFF;
    #pragma unroll
    for (int s = 0; s < JSPLIT; ++s) {
        float v = pos_val[s * N + row]; int ix = pos_idx[s * N + row];
        if (v > bpv || (v == bpv && ix < bpi)) { bpv = v; bpi = ix; }
        v = neg_val[s * N + row]; ix = neg_idx[s * N + row];
        if (v > bnv || (v == bnv && ix < bni)) { bnv = v; bni = ix; }
    }

    const float4 qi = ((const float4*)(q + row * D))[lane];
    const float4 qp = ((const float4*)(q + bpi * D))[lane];
    const float4 qn = ((const float4*)(q + bni * D))[lane];
    float dx, dp = 0.0f, dn = 0.0f;
    dx = qi.x - qp.x; dp += dx * dx;
    dx = qi.y - qp.y; dp += dx * dx;
    dx = qi.z - qp.z; dp += dx * dx;
    dx = qi.w - qp.w; dp += dx * dx;
    dx = qi.x - qn.x; dn += dx * dx;
    dx = qi.y - qn.y; dn += dx * dx;
    dx = qi.z - qn.z; dn += dx * dx;
    dx = qi.w - qn.w; dn += dx * dx;
    #pragma unroll
    for (int off = 32; off; off >>= 1) {
        dp += __shfl_down(dp, off, 64);
        dn += __shfl_down(dn, off, 64);
    }
    if (lane == 0) loss[row] = fmaxf(0.0f, (1.0f - dp) + dn);
}

// ---------------------------------------------------------------- kernel 4
// Deterministic mean (single block) — no atomics, no out-zeroing needed.
__global__ __launch_bounds__(256) void reduce_kernel(const float* __restrict__ loss,
                                                     float* __restrict__ out) {
    __shared__ float red[256];
    float s = 0.0f;
    for (int i = threadIdx.x; i < N; i += 256) s += loss[i];
    red[threadIdx.x] = s;
    __syncthreads();
    for (int off = 128; off; off >>= 1) {
        if (threadIdx.x < off) red[threadIdx.x] += red[threadIdx.x + off];
        __syncthreads();
    }
    if (threadIdx.x == 0) out[0] = red[0] * (1.0f / N);
}

// ----------------------------------------------------------------
extern "C" void kernel_launch(void* const* d_in, const int* in_sizes, int n_in,
                              void* d_out, int out_size, void* d_ws, size_t ws_size,
                              hipStream_t stream) {
    const float* q = (const float*)d_in[0];
    const int* tgt = (const int*)d_in[1];
    float* out = (float*)d_out;

    // workspace layout (floats/ints, all overwritten every call)
    float* sqv     = (float*)d_ws;              // [N]
    float* pos_val = sqv + N;                   // [JSPLIT*N]
    float* neg_val = pos_val + JSPLIT * N;      // [JSPLIT*N]
    float* loss    = neg_val + JSPLIT * N;      // [N]
    int*   pos_idx = (int*)(loss + N);          // [JSPLIT*N]
    int*   neg_idx = pos_idx + JSPLIT * N;      // [JSPLIT*N]

    sq_kernel<<<dim3(N / 4), dim3(256), 0, stream>>>(q, sqv);
    mine_kernel<<<dim3(N / TM, JSPLIT), dim3(256), 0, stream>>>(
        q, tgt, sqv, pos_val, neg_val, pos_idx, neg_idx);
    finalize_kernel<<<dim3(N / 4), dim3(256), 0, stream>>>(
        q, pos_val, neg_val, pos_idx, neg_idx, loss);
    reduce_kernel<<<dim3(1), dim3(256), 0, stream>>>(loss, out);
}

// Round 2
// 301.998 us; speedup vs baseline: 1.9023x; 1.9023x over previous
//
#include <hip/hip_runtime.h>

#define N 8192
#define D 256
#define JSPLIT 8
#define NEG_INF (-__builtin_inff())

typedef __bf16 bf16x8 __attribute__((ext_vector_type(8)));
typedef float f32x4 __attribute__((ext_vector_type(4)));

// async global->LDS, 16 bytes/lane; LDS dest is wave-uniform base + lane*16
__device__ __forceinline__ void gload16(const void* g, void* lds) {
    __builtin_amdgcn_global_load_lds(
        (const __attribute__((address_space(1))) void*)g,
        (__attribute__((address_space(3))) void*)lds, 16, 0, 0);
}

__device__ __forceinline__ unsigned short f2bf(float f) {
    unsigned int u = __float_as_uint(f);
    unsigned int r = (u + 0x7FFFu + ((u >> 16) & 1u)) >> 16;  // RNE
    return (unsigned short)r;
}
__device__ __forceinline__ float bf2f(unsigned short b) {
    return __uint_as_float(((unsigned int)b) << 16);
}

// ---------------------------------------------------------------- kernel 0
// split-bf16 decompose: qh = bf16(q), ql = bf16(q - float(qh))
__global__ __launch_bounds__(256) void convert_kernel(const float* __restrict__ q,
                                                      unsigned short* __restrict__ qh,
                                                      unsigned short* __restrict__ ql) {
    const int idx = (blockIdx.x * 256 + threadIdx.x) * 4;
    const float4 v = *(const float4*)(q + idx);
    ushort4 h, l;
    h.x = f2bf(v.x); l.x = f2bf(v.x - bf2f(h.x));
    h.y = f2bf(v.y); l.y = f2bf(v.y - bf2f(h.y));
    h.z = f2bf(v.z); l.z = f2bf(v.z - bf2f(h.z));
    h.w = f2bf(v.w); l.w = f2bf(v.w - bf2f(h.w));
    *(ushort4*)(qh + idx) = h;
    *(ushort4*)(ql + idx) = l;
}

// ---------------------------------------------------------------- kernel 1
// sq[i] = sum_d q[i][d]^2 (fp32, from original q) ; one wave per row
__global__ __launch_bounds__(256) void sq_kernel(const float* __restrict__ q,
                                                 float* __restrict__ sq) {
    const int row = blockIdx.x * 4 + (threadIdx.x >> 6);
    const int lane = threadIdx.x & 63;
    const float4 v = ((const float4*)(q + row * D))[lane];
    float s = v.x * v.x + v.y * v.y + v.z * v.z + v.w * v.w;
    #pragma unroll
    for (int off = 32; off; off >>= 1) s += __shfl_down(s, off, 64);
    if (lane == 0) sq[row] = s;
}

// ---------------------------------------------------------------- kernel 2
// MFMA split-bf16 miner. Block: 256 threads = 2x2 waves, 128x128 output tile,
// each wave 64x64 via 4x4 frags of 16x16x32. Grid (N/128, JSPLIT); each block
// scans 8 j-tiles, keeping per-row running argmax state in LDS.
__global__ __launch_bounds__(256) void mine_kernel(
    const unsigned short* __restrict__ qh, const unsigned short* __restrict__ ql,
    const int* __restrict__ tgt, const float* __restrict__ sqv,
    float* __restrict__ pos_val, int* __restrict__ pos_idx,
    float* __restrict__ neg_val, int* __restrict__ neg_idx)
{
    __shared__ unsigned short Ah[128 * 32], Al[128 * 32];
    __shared__ unsigned short Bh[128 * 32], Bl[128 * 32];
    __shared__ float bpvS[128], bnvS[128];
    __shared__ int   bpiS[128], bniS[128];

    const int i0 = blockIdx.x * 128;
    const int jsplit = blockIdx.y;

    const int tid = threadIdx.x;
    const int w = tid >> 6, lane = tid & 63;
    const int quad = lane >> 4, lc = lane & 15;
    const int wy = w >> 1, wx = w & 1;

    if (tid < 128) {
        bpvS[tid] = NEG_INF; bnvS[tid] = NEG_INF;
        bpiS[tid] = 0x7FFFFFFF; bniS[tid] = 0x7FFFFFFF;
    }

    for (int jj = 0; jj < N / 128 / JSPLIT; ++jj) {
        const int j0 = (jsplit * (N / 128 / JSPLIT) + jj) * 128;

        f32x4 acc[4][4];
        #pragma unroll
        for (int mt = 0; mt < 4; ++mt)
            #pragma unroll
            for (int nt = 0; nt < 4; ++nt) acc[mt][nt] = (f32x4){0.f, 0.f, 0.f, 0.f};

        for (int dk = 0; dk < D; dk += 32) {
            __syncthreads();  // previous chunk's frag reads / state init done
            #pragma unroll
            for (int it = 0; it < 2; ++it) {
                const int s = it * 256 + tid;          // 16B slot id, 0..511
                const int r = s >> 2, ko = (s & 3) * 8;
                const int lbase = (it * 256 + w * 64) * 16;  // wave-uniform bytes
                const size_t ga = (size_t)(i0 + r) * D + dk + ko;
                const size_t gb = (size_t)(j0 + r) * D + dk + ko;
                gload16(qh + ga, (char*)Ah + lbase);
                gload16(ql + ga, (char*)Al + lbase);
                gload16(qh + gb, (char*)Bh + lbase);
                gload16(ql + gb, (char*)Bl + lbase);
            }
            __syncthreads();

            bf16x8 fah[4], fal[4], fbh[4], fbl[4];
            #pragma unroll
            for (int t = 0; t < 4; ++t) {
                const int ar = (wy * 64 + t * 16 + lc) * 32 + quad * 8;
                const int br = (wx * 64 + t * 16 + lc) * 32 + quad * 8;
                fah[t] = *(const bf16x8*)&Ah[ar];
                fal[t] = *(const bf16x8*)&Al[ar];
                fbh[t] = *(const bf16x8*)&Bh[br];
                fbl[t] = *(const bf16x8*)&Bl[br];
            }
            #pragma unroll
            for (int mt = 0; mt < 4; ++mt)
                #pragma unroll
                for (int nt = 0; nt < 4; ++nt) {
                    acc[mt][nt] = __builtin_amdgcn_mfma_f32_16x16x32_bf16(
                        fah[mt], fbh[nt], acc[mt][nt], 0, 0, 0);
                    acc[mt][nt] = __builtin_amdgcn_mfma_f32_16x16x32_bf16(
                        fah[mt], fbl[nt], acc[mt][nt], 0, 0, 0);
                    acc[mt][nt] = __builtin_amdgcn_mfma_f32_16x16x32_bf16(
                        fal[mt], fbh[nt], acc[mt][nt], 0, 0, 0);
                }
        }

        // ---- epilogue for this 128x128 tile: masked argmax, exact
        // first-occurrence semantics (ascending col scan, strict >)
        float sqj[4]; int tj[4];
        #pragma unroll
        for (int nt = 0; nt < 4; ++nt) {
            const int col = j0 + wx * 64 + nt * 16 + lc;
            sqj[nt] = sqv[col]; tj[nt] = tgt[col];
        }
        #pragma unroll
        for (int mt = 0; mt < 4; ++mt) {
            #pragma unroll
            for (int reg = 0; reg < 4; ++reg) {
                const int sr = wy * 64 + mt * 16 + quad * 4 + reg;  // local row
                const int row = i0 + sr;
                const float si = sqv[row];
                const int ti = tgt[row];
                float bpv = NEG_INF, bnv = NEG_INF;
                int bpi = 0x7FFFFFFF, bni = 0x7FFFFFFF;
                #pragma unroll
                for (int nt = 0; nt < 4; ++nt) {
                    const int col = j0 + wx * 64 + nt * 16 + lc;
                    const float dist = fmaf(-2.0f, acc[mt][nt][reg], si + sqj[nt]);
                    const bool same = (ti == tj[nt]);
                    const bool dia = (row == col);
                    const float vp = dia ? NEG_INF : (same ? dist : 0.0f);
                    const float vn = dia ? NEG_INF : (same ? 0.0f : dist);
                    if (vp > bpv) { bpv = vp; bpi = col; }
                    if (vn > bnv) { bnv = vn; bni = col; }
                }
                #pragma unroll
                for (int off = 1; off < 16; off <<= 1) {  // within quad (16 lanes)
                    const float pv = __shfl_xor(bpv, off, 64);
                    const int   pi = __shfl_xor(bpi, off, 64);
                    if (pv > bpv || (pv == bpv && pi < bpi)) { bpv = pv; bpi = pi; }
                    const float nv = __shfl_xor(bnv, off, 64);
                    const int   ni = __shfl_xor(bni, off, 64);
                    if (nv > bnv || (nv == bnv && ni < bni)) { bnv = nv; bni = ni; }
                }
                if (lc == 0) {  // unique owner lane per row; no race, no barrier
                    if (bpv > bpvS[sr] || (bpv == bpvS[sr] && bpi < bpiS[sr])) {
                        bpvS[sr] = bpv; bpiS[sr] = bpi;
                    }
                    if (bnv > bnvS[sr] || (bnv == bnvS[sr] && bni < bniS[sr])) {
                        bnvS[sr] = bnv; bniS[sr] = bni;
                    }
                }
            }
        }
    }

    // final write: same owner lanes read their own LDS state
    #pragma unroll
    for (int mt = 0; mt < 4; ++mt)
        #pragma unroll
        for (int reg = 0; reg < 4; ++reg)
            if (lc == 0) {
                const int sr = wy * 64 + mt * 16 + quad * 4 + reg;
                const int row = i0 + sr;
                pos_val[jsplit * N + row] = bpvS[sr];
                pos_idx[jsplit * N + row] = bpiS[sr];
                neg_val[jsplit * N + row] = bnvS[sr];
                neg_idx[jsplit * N + row] = bniS[sr];
            }
}

// ---------------------------------------------------------------- kernel 3
// Merge split partials (ascending split = ascending idx), recompute exact
// fp32 distances like the reference, write per-row loss.
__global__ __launch_bounds__(256) void finalize_kernel(
    const float* __restrict__ q,
    const float* __restrict__ pos_val, const int* __restrict__ pos_idx,
    const float* __restrict__ neg_val, const int* __restrict__ neg_idx,
    float* __restrict__ loss)
{
    const int row = blockIdx.x * 4 + (threadIdx.x >> 6);
    const int lane = threadIdx.x & 63;

    float bpv = NEG_INF, bnv = NEG_INF;
    int bpi = 0x7FFFFFFF, bni = 0x7FFFFFFF;
    #pragma unroll
    for (int s = 0; s < JSPLIT; ++s) {
        float v = pos_val[s * N + row]; int ix = pos_idx[s * N + row];
        if (v > bpv || (v == bpv && ix < bpi)) { bpv = v; bpi = ix; }
        v = neg_val[s * N + row]; ix = neg_idx[s * N + row];
        if (v > bnv || (v == bnv && ix < bni)) { bnv = v; bni = ix; }
    }

    const float4 qi = ((const float4*)(q + row * D))[lane];
    const float4 qp = ((const float4*)(q + bpi * D))[lane];
    const float4 qn = ((const float4*)(q + bni * D))[lane];
    float dx, dp = 0.0f, dn = 0.0f;
    dx = qi.x - qp.x; dp += dx * dx;
    dx = qi.y - qp.y; dp += dx * dx;
    dx = qi.z - qp.z; dp += dx * dx;
    dx = qi.w - qp.w; dp += dx * dx;
    dx = qi.x - qn.x; dn += dx * dx;
    dx = qi.y - qn.y; dn += dx * dx;
    dx = qi.z - qn.z; dn += dx * dx;
    dx = qi.w - qn.w; dn += dx * dx;
    #pragma unroll
    for (int off = 32; off; off >>= 1) {
        dp += __shfl_down(dp, off, 64);
        dn += __shfl_down(dn, off, 64);
    }
    if (lane == 0) loss[row] = fmaxf(0.0f, (1.0f - dp) + dn);
}

// ---------------------------------------------------------------- kernel 4
__global__ __launch_bounds__(256) void reduce_kernel(const float* __restrict__ loss,
                                                     float* __restrict__ out) {
    __shared__ float red[256];
    float s = 0.0f;
    for (int i = threadIdx.x; i < N; i += 256) s += loss[i];
    red[threadIdx.x] = s;
    __syncthreads();
    for (int off = 128; off; off >>= 1) {
        if (threadIdx.x < off) red[threadIdx.x] += red[threadIdx.x + off];
        __syncthreads();
    }
    if (threadIdx.x == 0) out[0] = red[0] * (1.0f / N);
}

// ----------------------------------------------------------------
extern "C" void kernel_launch(void* const* d_in, const int* in_sizes, int n_in,
                              void* d_out, int out_size, void* d_ws, size_t ws_size,
                              hipStream_t stream) {
    const float* q = (const float*)d_in[0];
    const int* tgt = (const int*)d_in[1];
    float* out = (float*)d_out;

    // ws layout (~9.5 MB)
    unsigned short* qh = (unsigned short*)d_ws;     // N*D bf16 bits
    unsigned short* ql = qh + (size_t)N * D;        // N*D
    float* sqv     = (float*)(ql + (size_t)N * D);  // N
    float* pos_val = sqv + N;                       // JSPLIT*N
    float* neg_val = pos_val + JSPLIT * N;          // JSPLIT*N
    float* loss    = neg_val + JSPLIT * N;          // N
    int*   pos_idx = (int*)(loss + N);              // JSPLIT*N
    int*   neg_idx = pos_idx + JSPLIT * N;          // JSPLIT*N

    convert_kernel<<<dim3(N * D / 1024), dim3(256), 0, stream>>>(q, qh, ql);
    sq_kernel<<<dim3(N / 4), dim3(256), 0, stream>>>(q, sqv);
    mine_kernel<<<dim3(N / 128, JSPLIT), dim3(256), 0, stream>>>(
        qh, ql, tgt, sqv, pos_val, pos_idx, neg_val, neg_idx);
    finalize_kernel<<<dim3(N / 4), dim3(256), 0, stream>>>(
        q, pos_val, pos_idx, neg_val, neg_idx, loss);
    reduce_kernel<<<dim3(1), dim3(256), 0, stream>>>(loss, out);
}